// Round 1
// baseline (232.297 us; speedup 1.0000x reference)
//
#include <hip/hip_runtime.h>

// FFB encoder fused kernel, MI355X (gfx950). Round 12.
//  Theory: R11 counters showed MfmaUtil 33%, VALUBusy 45% (incl MFMA), no pipe
//  saturated; largest reducible consumer = LDS instruction count
//  (128 wave-ops/layer: 32 G1 reads + 64 u16 epilogue writes + 32 head reads).
//  Two layout changes cut it to 64:
//   (1) GEMM1/grid operand SWAP (wh,gf as A-operand; x,g as B). A/B frag
//       layouts are symmetric (lane&31 = row resp. col, 8 consec k), so packed
//       wh/gf work unchanged as A and row-major s_x works unchanged as B.
//       C/D layout (col=lane&31=x-row, reg pattern=W-col) gives each reg quad
//       4 CONSECUTIVE W-cols -> epilogue = 16 packed ds_write_b64 per
//       wave-layer instead of 64 ds_write_u16. RNE f16 kept (_Float16 casts,
//       compiler packs). Bias is now reg-indexed -> C1 init from K5-prescaled
//       bhs[] (v4f loads; bhs/bhhs produced by ffb_pack).
//   (2) Head GEMM 16x16x32 -> 32x32x16: wave = one 32x32 output quadrant;
//       A-frags halve (16 b128, reusing GEMM1's a1off bases), whh repacked to
//       32-col tiles (same bytes), out-store 32-lane contiguous, bias one
//       scalar per lane.
//  Kept from R9-R11: TM=64, stride-264 LDS, 2 barriers/layer, GEMM1 B-ring
//  depth 3, __launch_bounds__(256,3) (R10 lesson: (256,4) spills),
//  grid branch hi-only (gf pre-scaled 2^(l-1)).

#define TM 64
#define XSTRIDE 264
#define GSTRIDE 48
#define K5 0.79577471545947667f         // 5/(2*pi)

typedef __attribute__((ext_vector_type(8))) _Float16 v8h;
typedef __attribute__((ext_vector_type(4))) _Float16 v4h;
typedef __attribute__((ext_vector_type(4))) float v4f;
typedef __attribute__((ext_vector_type(16))) float v16f;

#define MFMA32H(a, b, c) __builtin_amdgcn_mfma_f32_32x32x16_f16(a, b, c, 0, 0, 0)

__device__ __forceinline__ float sin_rev(float u) {
#if __has_builtin(__builtin_amdgcn_fractf)
    return __builtin_amdgcn_sinf(__builtin_amdgcn_fractf(u));
#else
    return __builtin_amdgcn_sinf(u - floorf(u));
#endif
}

__device__ __forceinline__ short f16s(float x) {      // RNE f32->f16
    _Float16 hh = (_Float16)x;
    return __builtin_bit_cast(short, hh);
}

// ---------------- weight packing ----------------
// wh   f16: [l][kb16][nt8][lane64][8]  (327680 shorts), scaled by K5
// whh  f16: [l][kb16][nt2][lane64][8]  (81920 shorts),  scaled by K5  (32-col tiles)
// gf   f16: [l][nt8][lane64][8]        (20480 shorts),  ffnA*2^(l-1)
// bhs  f32: [l][256]  = bh*K5          (1280 floats)
// bhhs f32: [l][64]   = bhh*K5         (320 floats)
__global__ __launch_bounds__(256) void ffb_pack(
    const float* __restrict__ Wh, const float* __restrict__ Whh,
    const float* __restrict__ ffnA,
    const float* __restrict__ bh, const float* __restrict__ bhh,
    short* __restrict__ wh, short* __restrict__ whh, short* __restrict__ gf,
    float* __restrict__ bhs, float* __restrict__ bhhs)
{
    int t = blockIdx.x * 256 + threadIdx.x;
    if (t < 40960) {                       // (l, kb, nt, lane)
        int lane = t & 63, nt = (t >> 6) & 7, kb = (t >> 9) & 15, l = t >> 13;
        int n = nt * 32 + (lane & 31);
        int k0 = kb * 16 + (lane >> 5) * 8;
        short hs[8];
        #pragma unroll
        for (int jj = 0; jj < 8; jj++)
            hs[jj] = f16s(Wh[(l * 256 + k0 + jj) * 256 + n] * K5);
        *(v8h*)(wh + t * 8) = *(v8h*)hs;
    } else if (t < 51200) {
        int t2 = t - 40960;                // (l, kb16, nt2, lane)
        int lane = t2 & 63, nt = (t2 >> 6) & 1, kb = (t2 >> 7) & 15, l = t2 >> 11;
        int n = nt * 32 + (lane & 31);
        int k0 = kb * 16 + (lane >> 5) * 8;
        short hs[8];
        #pragma unroll
        for (int jj = 0; jj < 8; jj++)
            hs[jj] = f16s(Whh[(l * 256 + k0 + jj) * 64 + n] * K5);
        *(v8h*)(whh + t2 * 8) = *(v8h*)hs;
    } else if (t < 53760) {
        int t3 = t - 51200;                // (l, nt, lane)
        int lane = t3 & 63, nt = (t3 >> 6) & 7, l = t3 >> 9;
        int n = nt * 32 + (lane & 31);
        const float sc = 0.5f * (float)(1 << l);       // 2^(l-1), exact
        short hs[8];
        #pragma unroll
        for (int jj = 0; jj < 8; jj++)
            hs[jj] = f16s(ffnA[(l * 8 + jj) * 256 + n] * sc);
        *(v8h*)(gf + t3 * 8) = *(v8h*)hs;
    } else if (t < 55040) {
        int t4 = t - 53760;
        bhs[t4] = bh[t4] * K5;
    } else if (t < 55360) {
        int t5 = t - 55040;
        bhhs[t5] = bhh[t5] * K5;
    }
}

// ---------------- main fused kernel ----------------
__global__ __launch_bounds__(256, 3) void ffb_main(
    const float* __restrict__ pos, const float* __restrict__ gfeat,
    const float* __restrict__ W0, const float* __restrict__ b0,
    const float* __restrict__ bhs, const float* __restrict__ bhhs,
    const short* __restrict__ wh, const short* __restrict__ whh,
    const short* __restrict__ gf,
    float* __restrict__ out)
{
    __shared__ __align__(16) short s_x[TM * XSTRIDE];   // f16  (33792 B)
    __shared__ __align__(16) short s_g[TM * GSTRIDE];   // f16  (6144 B)
    __shared__ float s_pos[TM * 3];                     //      (768 B)

    const int tid = threadIdx.x;
    const int row0 = blockIdx.x * TM;
    const int lane = tid & 63;
    const int w = tid >> 6;
    const int m32 = lane & 31;
    const int h = lane >> 5;
    const int mq = w >> 1;                 // head-GEMM quadrant row-tile
    const int tq = w & 1;                  // head-GEMM quadrant col-tile

    if (tid < TM * 3) s_pos[tid] = pos[row0 * 3 + tid];
    for (int k2 = tid; k2 < TM * 40; k2 += 256) {
        int r = k2 / 40, f = k2 % 40;
        s_g[r * GSTRIDE + f] = f16s(gfeat[row0 * 40 + k2]);
    }
    __syncthreads();

    // layer 0: x = sin(5*(pos@W0 + b0))
    {
        const int c = tid;
        const float w00 = W0[c], w01 = W0[256 + c], w02 = W0[512 + c], bc = b0[c];
        #pragma unroll 4
        for (int r = 0; r < TM; r++) {
            float d = s_pos[r * 3 + 0] * w00 + s_pos[r * 3 + 1] * w01
                    + s_pos[r * 3 + 2] * w02 + bc;
            s_x[r * XSTRIDE + c] = f16s(sin_rev(d * K5));
        }
    }
    __syncthreads();

    float cout[16];
    #pragma unroll
    for (int r = 0; r < 16; r++) cout[r] = 0.f;

    const int a1off0 = m32 * XSTRIDE + h * 8;            // x-row tile 0, + kb*16
    const int a1off1 = (32 + m32) * XSTRIDE + h * 8;     // x-row tile 1

    for (int l = 0; l < 5; l++) {
        // ---- C1 init: per-W-col bias (K5-prescaled), same for both m-tiles ----
        // wcol(reg r, h) = w*64 + tt*32 + 8*(r>>2) + 4*h + (r&3)
        v16f C1[2][2];
        {
            const float* bl = bhs + l * 256 + w * 64 + h * 4;
            #pragma unroll
            for (int tt = 0; tt < 2; tt++)
                #pragma unroll
                for (int rq = 0; rq < 4; rq++) {
                    v4f b = *(const v4f*)(bl + tt * 32 + rq * 8);
                    #pragma unroll
                    for (int j = 0; j < 4; j++) {
                        C1[0][tt][rq * 4 + j] = b[j];
                        C1[1][tt][rq * 4 + j] = b[j];
                    }
                }
        }
        v8h gb0 = *(const v8h*)(gf + ((l * 8 + w * 2 + 0) * 64 + lane) * 8);
        v8h gb1 = *(const v8h*)(gf + ((l * 8 + w * 2 + 1) * 64 + lane) * 8);

        // ---- GEMM1 (SWAPPED): wh-frag = A, x-frag = B; 3-deep B-ring ----
        {
            const short* bp = wh + l * 65536 + (2 * w) * 512 + lane * 8;
            v8h rb0[4], rb1[4];
            #pragma unroll
            for (int p = 0; p < 3; p++) {
                rb0[p] = *(const v8h*)(bp + p * 4096);
                rb1[p] = *(const v8h*)(bp + p * 4096 + 512);
            }
            #pragma unroll
            for (int kb = 0; kb < 16; kb++) {
                if (kb + 3 < 16) {
                    rb0[(kb + 3) & 3] = *(const v8h*)(bp + (kb + 3) * 4096);
                    rb1[(kb + 3) & 3] = *(const v8h*)(bp + (kb + 3) * 4096 + 512);
                }
                v8h a0 = *(const v8h*)&s_x[a1off0 + kb * 16];
                v8h a1 = *(const v8h*)&s_x[a1off1 + kb * 16];
                v8h bc0 = rb0[kb & 3], bc1 = rb1[kb & 3];
                C1[0][0] = MFMA32H(bc0, a0, C1[0][0]);
                C1[0][1] = MFMA32H(bc1, a0, C1[0][1]);
                C1[1][0] = MFMA32H(bc0, a1, C1[1][0]);
                C1[1][1] = MFMA32H(bc1, a1, C1[1][1]);
            }
        }
        __syncthreads();   // all waves done reading x_l

        // ---- epilogue: x = sin(C1) + sin(G); lane = fixed x-row, reg quads =
        //      4 consecutive W-cols -> packed b64 stores ----
        #pragma unroll
        for (int m = 0; m < 2; m++) {
            v8h ga = *(const v8h*)&s_g[(m * 32 + m32) * GSTRIDE + l * 8];
            const int rowb = (m * 32 + m32) * XSTRIDE;
            #pragma unroll
            for (int tt = 0; tt < 2; tt++) {
                v16f Z = {};
                v16f G = MFMA32H((tt ? gb1 : gb0), ga, Z);
                const int cb = rowb + w * 64 + tt * 32 + h * 4;
                #pragma unroll
                for (int rq = 0; rq < 4; rq++) {
                    v4h pv;
                    #pragma unroll
                    for (int j = 0; j < 4; j++)
                        pv[j] = (_Float16)(sin_rev(C1[m][tt][rq * 4 + j])
                                         + sin_rev(G[rq * 4 + j]));
                    *(v4h*)(s_x + cb + rq * 8) = pv;    // 8B aligned
                }
            }
        }
        __syncthreads();   // new x visible

        // ---- head GEMM, 32x32x16: wave = quadrant (mq,tq); x = A (reuses
        //      a1off bases), whh 32-col tiles = B; 16 b128 A-reads ----
        {
            const float b2 = bhhs[l * 64 + tq * 32 + m32];
            v16f C2;
            #pragma unroll
            for (int r = 0; r < 16; r++) C2[r] = b2;
            const short* bp2 = whh + l * 16384 + tq * 512 + lane * 8;
            v8h bc[16];
            #pragma unroll
            for (int kb = 0; kb < 16; kb++)
                bc[kb] = *(const v8h*)(bp2 + kb * 1024);
            const int aoff = mq ? a1off1 : a1off0;
            #pragma unroll
            for (int kb = 0; kb < 16; kb++) {
                v8h a = *(const v8h*)&s_x[aoff + kb * 16];
                C2 = MFMA32H(a, bc[kb], C2);
            }
            #pragma unroll
            for (int r = 0; r < 16; r++) cout[r] += sin_rev(C2[r]);
        }
        // no barrier: next GEMM1 reads same x; overwrites after its own barrier
    }

    // ---- store x_out: row = mq*32 + regpat, col = tq*32 + m32 (32-wide) ----
    #pragma unroll
    for (int r = 0; r < 16; r++) {
        const int orow = row0 + mq * 32 + (r & 3) + 8 * (r >> 2) + 4 * h;
        out[orow * 64 + tq * 32 + m32] = cout[r];
    }
}

extern "C" void kernel_launch(void* const* d_in, const int* in_sizes, int n_in,
                              void* d_out, int out_size, void* d_ws, size_t ws_size,
                              hipStream_t stream) {
    const float* pos   = (const float*)d_in[0];
    const float* gfeat = (const float*)d_in[1];
    const float* ffnA  = (const float*)d_in[2];
    const float* W0    = (const float*)d_in[3];
    const float* b0    = (const float*)d_in[4];
    const float* Wh    = (const float*)d_in[5];
    const float* bh    = (const float*)d_in[6];
    const float* Whh   = (const float*)d_in[7];
    const float* bhh   = (const float*)d_in[8];
    float* out = (float*)d_out;
    const int N = in_sizes[0] / 3;

    // ws: wh 327680 | whh 81920 | gf 20480 shorts, then bhs 1280 | bhhs 320 f32
    short* wh  = (short*)d_ws;
    short* whh = wh + 327680;
    short* gf  = whh + 81920;
    float* bhs  = (float*)(gf + 20480);     // byte offset 860160, 16B aligned
    float* bhhs = bhs + 1280;

    ffb_pack<<<217, 256, 0, stream>>>(Wh, Whh, ffnA, bh, bhh,
                                      wh, whh, gf, bhs, bhhs);
    ffb_main<<<N / TM, 256, 0, stream>>>(pos, gfeat, W0, b0, bhs, bhhs,
                                         wh, whh, gf, out);
}